// Round 1
// baseline (4456.812 us; speedup 1.0000x reference)
//
#include <hip/hip_runtime.h>

using u16 = unsigned short;
using u32 = unsigned int;

typedef __attribute__((ext_vector_type(8))) short bf16x8;
typedef __attribute__((ext_vector_type(4))) float f32x4;

#define EPI_F32    0
#define EPI_ADDRES 1
#define EPI_GELU   2

__device__ __forceinline__ u16 f2bf(float f) {
  u32 u = __builtin_bit_cast(u32, f);
  u += 0x7fffu + ((u >> 16) & 1u);
  return (u16)(u >> 16);
}
__device__ __forceinline__ float bf2f(u16 h) {
  u32 u = ((u32)h) << 16;
  return __builtin_bit_cast(float, u);
}

// async global->LDS, 16B per lane (dest must be wave-uniform base + lane*16)
__device__ __forceinline__ void gld16(u16* lds, const u16* g) {
  __builtin_amdgcn_global_load_lds(
      (const __attribute__((address_space(1))) unsigned int*)(const void*)g,
      (__attribute__((address_space(3))) unsigned int*)(void*)lds, 16, 0, 0);
}

// ---------------- embedding: x = embed[ids] + pos ----------------
__launch_bounds__(256)
__global__ void embed_k(const int* __restrict__ ids, const float* __restrict__ emb,
                        const float* __restrict__ pos, float* __restrict__ x)
{
  int row = blockIdx.x;          // token index 0..2047
  int t = row & 1023;
  int id = ids[row];
  int c = threadIdx.x * 4;
  const float4 e = *(const float4*)(emb + (size_t)id * 1024 + c);
  const float4 p = *(const float4*)(pos + (size_t)t * 1024 + c);
  float4 r; r.x = e.x + p.x; r.y = e.y + p.y; r.z = e.z + p.z; r.w = e.w + p.w;
  *(float4*)(x + (size_t)row * 1024 + c) = r;
}

// ---------------- RMSNorm over D=1024, fp32 in -> bf16 out ----------------
__launch_bounds__(256)
__global__ void rmsnorm_k(const float* __restrict__ x, const float* __restrict__ wgt,
                          u16* __restrict__ out)
{
  int row = blockIdx.x;
  int tid = threadIdx.x;
  int c = tid * 4;
  const float4 v = *(const float4*)(x + (size_t)row * 1024 + c);
  float ss = v.x * v.x + v.y * v.y + v.z * v.z + v.w * v.w;
  #pragma unroll
  for (int off = 1; off < 64; off <<= 1) ss += __shfl_xor(ss, off, 64);
  __shared__ float red[4];
  int w = tid >> 6;
  if ((tid & 63) == 0) red[w] = ss;
  __syncthreads();
  ss = red[0] + red[1] + red[2] + red[3];
  float rs = rsqrtf(ss * (1.0f / 1024.0f) + 1e-5f);
  const float4 g = *(const float4*)(wgt + c);
  u16* o = out + (size_t)row * 1024 + c;
  o[0] = f2bf(v.x * g.x * rs);
  o[1] = f2bf(v.y * g.y * rs);
  o[2] = f2bf(v.z * g.z * rs);
  o[3] = f2bf(v.w * g.w * rs);
}

// ---------------- per-head QK-norm (HD=64) + V cast ----------------
__launch_bounds__(256)
__global__ void qkvnorm_k(const float* __restrict__ qr, const float* __restrict__ kr,
                          const float* __restrict__ vr,
                          const float* __restrict__ qw, const float* __restrict__ kw,
                          u16* __restrict__ qb, u16* __restrict__ kb, u16* __restrict__ vb)
{
  int row = blockIdx.x;          // token
  int tid = threadIdx.x, w = tid >> 6, lane = tid & 63;
  float qwl = qw[lane], kwl = kw[lane];
  #pragma unroll
  for (int hh = 0; hh < 4; hh++) {
    int h = w * 4 + hh;
    size_t idx = (size_t)row * 1024 + h * 64 + lane;
    float qv = qr[idx];
    float kv = kr[idx];
    float sq = qv * qv, sk = kv * kv;
    #pragma unroll
    for (int off = 1; off < 64; off <<= 1) {
      sq += __shfl_xor(sq, off, 64);
      sk += __shfl_xor(sk, off, 64);
    }
    qb[idx] = f2bf(qv * rsqrtf(sq * (1.0f / 64.0f) + 1e-5f) * qwl);
    kb[idx] = f2bf(kv * rsqrtf(sk * (1.0f / 64.0f) + 1e-5f) * kwl);
  }
  size_t base = (size_t)row * 1024 + tid * 4;
  const float4 v4 = *(const float4*)(vr + base);
  u16* o = vb + base;
  o[0] = f2bf(v4.x); o[1] = f2bf(v4.y); o[2] = f2bf(v4.z); o[3] = f2bf(v4.w);
}

// ---------------- weight transpose+cast: f32 [K][N] -> bf16 [Npad][K] ----------------
// grid: (K/64, Npad/64, nz); z selects among up to 4 source matrices.
// Rows n >= N are zero-filled (pads LM head to a multiple of 128).
__launch_bounds__(256)
__global__ void convw_k(const float* __restrict__ Wa, const float* __restrict__ Wb,
                        const float* __restrict__ Wc, const float* __restrict__ Wd,
                        u16* __restrict__ out, int K, int N, size_t ostride)
{
  const float* W = blockIdx.z == 0 ? Wa : blockIdx.z == 1 ? Wb : blockIdx.z == 2 ? Wc : Wd;
  u16* o = out + (size_t)blockIdx.z * ostride;
  const int k0 = blockIdx.x * 64, n0 = blockIdx.y * 64;
  __shared__ u16 t[64][72];      // [n][k], pad 72
  const int tid = threadIdx.x;
  const bool n4 = (N & 3) == 0;
  #pragma unroll
  for (int i = 0; i < 4; i++) {
    int c = (tid + i * 256) * 4;
    int r = c >> 6, col = c & 63;
    int gn = n0 + col;
    const float* wp = W + (size_t)(k0 + r) * N + gn;
    float v0, v1, v2, v3;
    if (n4) {                    // N%4==0 -> row base 16B aligned, gn+3 < N guaranteed
      const float4 v = *(const float4*)wp;
      v0 = v.x; v1 = v.y; v2 = v.z; v3 = v.w;
    } else {
      v0 = (gn     < N) ? wp[0] : 0.0f;
      v1 = (gn + 1 < N) ? wp[1] : 0.0f;
      v2 = (gn + 2 < N) ? wp[2] : 0.0f;
      v3 = (gn + 3 < N) ? wp[3] : 0.0f;
    }
    t[col + 0][r] = f2bf(v0);
    t[col + 1][r] = f2bf(v1);
    t[col + 2][r] = f2bf(v2);
    t[col + 3][r] = f2bf(v3);
  }
  __syncthreads();
  #pragma unroll
  for (int i = 0; i < 2; i++) {
    int c2 = tid + i * 256;
    int n = c2 >> 3, kc = (c2 & 7) * 8;
    *(int4*)(o + (size_t)(n0 + n) * K + k0 + kc) = *(const int4*)&t[n][kc];
  }
}

// ---------------- GEMM (bf16 x bf16): C[M=2048,N] = A[M,K] x Wt^T, Wt is [Npad][K] bf16 ----
// m97 structure: both operands staged via global_load_lds width-16, linear [.][64] LDS,
// 128x128 tile, BK=64, 4 waves each 64x64 via 4x4 16x16x32 MFMAs, 2-barrier loop.
__launch_bounds__(256, 2)
__global__ void gemm128b(const u16* __restrict__ A,
                         const u16* __restrict__ Wa,
                         const u16* __restrict__ Wb,
                         const u16* __restrict__ Wc,
                         int N, int K,
                         float* outF,
                         u16* __restrict__ outB,
                         const float* res,
                         int epi, size_t zstride)
{
  const int R = 16;                       // M/128
  const int S = (N + 127) >> 7;
  const int z = blockIdx.z;
  const u16* W = (z == 0) ? Wa : ((z == 1) ? Wb : Wc);
  float* oF = outF + (size_t)z * zstride;

  // XCD-aware swizzle (same as verified gemm128)
  int bid = blockIdx.x;
  int strip, mb;
  int fullB = (S >> 3) * (8 * R);
  if (bid < fullB) {
    int g8 = bid / (8 * R);
    int rem = bid - g8 * (8 * R);
    strip = g8 * 8 + (rem & 7);
    mb = rem >> 3;
  } else {
    int r2 = bid - fullB;
    int S2 = S - ((S >> 3) << 3);
    strip = ((S >> 3) << 3) + r2 % S2;
    mb = r2 / S2;
  }
  const int bm = mb * 128, bn = strip * 128;

  __shared__ alignas(16) u16 As[128 * 64];   // [m][k] linear (global_load_lds dest)
  __shared__ alignas(16) u16 Bs[128 * 64];   // [n][k] linear

  const int tid = threadIdx.x;
  const int w = tid >> 6, lane = tid & 63;
  const int g = lane >> 4, l15 = lane & 15;
  const int mh = (w >> 1) * 64, nh = (w & 1) * 64;

  f32x4 acc[4][4] = {};

  const u16* ap[4]; const u16* bp[4]; u16* al[4]; u16* bl[4];
  #pragma unroll
  for (int i = 0; i < 4; i++) {
    int c = tid + i * 256;
    al[i] = &As[(size_t)c * 8];            // byte offset c*16 = wave base + lane*16
    bl[i] = &Bs[(size_t)c * 8];
    ap[i] = A + (size_t)(bm + (c >> 3)) * K + (c & 7) * 8;
    bp[i] = W + (size_t)(bn + (c >> 3)) * K + (c & 7) * 8;
  }

  for (int k0 = 0; k0 < K; k0 += 64) {
    __syncthreads();                        // prior iteration's LDS reads done
    #pragma unroll
    for (int i = 0; i < 4; i++) {
      gld16(al[i], ap[i] + k0);
      gld16(bl[i], bp[i] + k0);
    }
    __syncthreads();                        // drains vmcnt(0): tiles ready
    #pragma unroll
    for (int ks = 0; ks < 2; ks++) {
      bf16x8 af[4], bfr[4];
      #pragma unroll
      for (int i = 0; i < 4; i++)
        af[i] = *(const bf16x8*)&As[(mh + i * 16 + l15) * 64 + ks * 32 + g * 8];
      #pragma unroll
      for (int j = 0; j < 4; j++)
        bfr[j] = *(const bf16x8*)&Bs[(nh + j * 16 + l15) * 64 + ks * 32 + g * 8];
      #pragma unroll
      for (int i = 0; i < 4; i++)
        #pragma unroll
        for (int j = 0; j < 4; j++)
          acc[i][j] = __builtin_amdgcn_mfma_f32_16x16x32_bf16(af[i], bfr[j], acc[i][j], 0, 0, 0);
    }
  }

  // epilogue: C layout col=lane&15, row=(lane>>4)*4+reg  [m89-verified]
  #pragma unroll
  for (int i = 0; i < 4; i++) {
    int gm = bm + mh + i * 16 + g * 4;
    #pragma unroll
    for (int j = 0; j < 4; j++) {
      int gn = bn + nh + j * 16 + l15;
      f32x4 a = acc[i][j];
      if (epi == EPI_F32) {
        if (gn < N) {
          #pragma unroll
          for (int r = 0; r < 4; r++) oF[(size_t)(gm + r) * N + gn] = a[r];
        }
      } else if (epi == EPI_ADDRES) {
        #pragma unroll
        for (int r = 0; r < 4; r++) {
          size_t o = (size_t)(gm + r) * N + gn;
          oF[o] = res[o] + a[r];
        }
      } else {
        #pragma unroll
        for (int r = 0; r < 4; r++) {
          float xg = a[r];
          float ge = 0.5f * xg * (1.0f + erff(xg * 0.70710678118f));
          outB[(size_t)(gm + r) * N + gn] = f2bf(ge);
        }
      }
    }
  }
}

// ---------------- fallback GEMM: C[M=2048,N] = A(bf16)[M,K] x W(f32)[K,N] ----------------
// (previous verified kernel, used only when workspace is too small for preconversion)
__launch_bounds__(256, 2)
__global__ void gemm128(const u16* __restrict__ A,
                        const float* __restrict__ Wa,
                        const float* __restrict__ Wb,
                        const float* __restrict__ Wc,
                        int N, int K,
                        float* outF,
                        u16* __restrict__ outB,
                        const float* res,
                        int epi, size_t zstride)
{
  const int R = 16;
  const int S = (N + 127) >> 7;
  const int z = blockIdx.z;
  const float* W = (z == 0) ? Wa : ((z == 1) ? Wb : Wc);
  float* oF = outF + (size_t)z * zstride;

  int bid = blockIdx.x;
  int strip, mb;
  int fullB = (S >> 3) * (8 * R);
  if (bid < fullB) {
    int g8 = bid / (8 * R);
    int rem = bid - g8 * (8 * R);
    strip = g8 * 8 + (rem & 7);
    mb = rem >> 3;
  } else {
    int r2 = bid - fullB;
    int S2 = S - ((S >> 3) << 3);
    strip = ((S >> 3) << 3) + r2 % S2;
    mb = r2 / S2;
  }
  const int bm = mb * 128, bn = strip * 128;

  __shared__ alignas(16) u16 As[128 * 64];
  __shared__ alignas(16) u16 Bs[128 * 72];

  const int tid = threadIdx.x;
  const int w = tid >> 6, lane = tid & 63;
  const int g = lane >> 4, l15 = lane & 15;
  const int mh = (w >> 1) * 64, nh = (w & 1) * 64;

  f32x4 acc[4][4] = {};
  const bool n4 = (N & 3) == 0;

  for (int k0 = 0; k0 < K; k0 += 64) {
    int4 av[4];
    #pragma unroll
    for (int i = 0; i < 4; i++) {
      int c = tid + i * 256;
      av[i] = *(const int4*)(A + (size_t)(bm + (c >> 3)) * K + k0 + (c & 7) * 8);
    }
    float wv[8][4];
    #pragma unroll
    for (int i = 0; i < 8; i++) {
      int c2 = tid + i * 256;
      int kl = c2 >> 5, n0 = (c2 & 31) * 4;
      int gn = bn + n0;
      const float* wp = W + (size_t)(k0 + kl) * N + gn;
      if (n4) {
        const float4 t4 = *(const float4*)wp;
        wv[i][0] = t4.x; wv[i][1] = t4.y; wv[i][2] = t4.z; wv[i][3] = t4.w;
      } else {
        #pragma unroll
        for (int d = 0; d < 4; d++) wv[i][d] = (gn + d < N) ? wp[d] : 0.0f;
      }
    }
    __syncthreads();
    #pragma unroll
    for (int i = 0; i < 4; i++) {
      int c = tid + i * 256;
      *(int4*)&As[(c >> 3) * 64 + (c & 7) * 8] = av[i];
    }
    #pragma unroll
    for (int i = 0; i < 8; i++) {
      int c2 = tid + i * 256;
      int kl = c2 >> 5, n0 = (c2 & 31) * 4;
      u16* bp = &Bs[n0 * 72 + kl];
      bp[0]   = f2bf(wv[i][0]);
      bp[72]  = f2bf(wv[i][1]);
      bp[144] = f2bf(wv[i][2]);
      bp[216] = f2bf(wv[i][3]);
    }
    __syncthreads();
    #pragma unroll
    for (int ks = 0; ks < 2; ks++) {
      bf16x8 af[4], bfr[4];
      #pragma unroll
      for (int i = 0; i < 4; i++)
        af[i] = *(const bf16x8*)&As[(mh + i * 16 + l15) * 64 + ks * 32 + g * 8];
      #pragma unroll
      for (int j = 0; j < 4; j++)
        bfr[j] = *(const bf16x8*)&Bs[(nh + j * 16 + l15) * 72 + ks * 32 + g * 8];
      #pragma unroll
      for (int i = 0; i < 4; i++)
        #pragma unroll
        for (int j = 0; j < 4; j++)
          acc[i][j] = __builtin_amdgcn_mfma_f32_16x16x32_bf16(af[i], bfr[j], acc[i][j], 0, 0, 0);
    }
  }

  #pragma unroll
  for (int i = 0; i < 4; i++) {
    int gm = bm + mh + i * 16 + g * 4;
    #pragma unroll
    for (int j = 0; j < 4; j++) {
      int gn = bn + nh + j * 16 + l15;
      f32x4 a = acc[i][j];
      if (epi == EPI_F32) {
        if (gn < N) {
          #pragma unroll
          for (int r = 0; r < 4; r++) oF[(size_t)(gm + r) * N + gn] = a[r];
        }
      } else if (epi == EPI_ADDRES) {
        #pragma unroll
        for (int r = 0; r < 4; r++) {
          size_t o = (size_t)(gm + r) * N + gn;
          oF[o] = res[o] + a[r];
        }
      } else {
        #pragma unroll
        for (int r = 0; r < 4; r++) {
          float xg = a[r];
          float ge = 0.5f * xg * (1.0f + erff(xg * 0.70710678118f));
          outB[(size_t)(gm + r) * N + gn] = f2bf(ge);
        }
      }
    }
  }
}

// ---------------- fused causal attention + gate + value-residual ----------------
__launch_bounds__(256, 2)
__global__ void attn_k(const u16* __restrict__ Qb, const u16* __restrict__ Kbf,
                       const u16* __restrict__ Vbf, const float* __restrict__ gate,
                       u16* __restrict__ O)
{
  __shared__ alignas(16) u16 Qs[64 * 64];     // [qrow][hd]
  __shared__ alignas(16) u16 Ks[64 * 64];     // [krow][hd]
  __shared__ alignas(16) u16 Vt[64 * 72];     // [hd][krow] (transposed, pad 72)
  __shared__ alignas(16) u16 Ps[4][16 * 72];  // per-wave P tile [qrow][krow]

  int bid = blockIdx.x;
  int g8 = bid >> 7;
  int rem = bid & 127;
  int bh = g8 * 8 + (rem & 7);   // same (b,h) pinned to one XCD -> K/V stay in L2
  int qt = rem >> 3;
  int b = bh >> 4, h = bh & 15;

  const int tid = threadIdx.x;
  const int w = tid >> 6, lane = tid & 63;
  const int g = lane >> 4, l15 = lane & 15;

  const size_t base = (size_t)b * 1024 * 1024 + (size_t)h * 64;
  const int qbase = qt * 64;

  #pragma unroll
  for (int i = 0; i < 2; i++) {
    int c = tid + i * 256;
    int r = c >> 3, c0 = (c & 7) * 8;
    *(int4*)&Qs[r * 64 + c0] = *(const int4*)(Qb + base + (size_t)(qbase + r) * 1024 + c0);
  }
  __syncthreads();

  bf16x8 aq[2];
  aq[0] = *(const bf16x8*)&Qs[(w * 16 + l15) * 64 + g * 8];
  aq[1] = *(const bf16x8*)&Qs[(w * 16 + l15) * 64 + 32 + g * 8];

  float m_i[4], l_i[4];
  f32x4 acco[4] = {};
  #pragma unroll
  for (int r = 0; r < 4; r++) { m_i[r] = -1e30f; l_i[r] = 0.0f; }

  const float scale = 0.125f;

  for (int kt = 0; kt <= qt; kt++) {
    const int kk = kt * 64;
    __syncthreads();
    #pragma unroll
    for (int i = 0; i < 2; i++) {
      int c = tid + i * 256;
      int r = c >> 3, c0 = (c & 7) * 8;
      *(int4*)&Ks[r * 64 + c0] = *(const int4*)(Kbf + base + (size_t)(kk + r) * 1024 + c0);
    }
    #pragma unroll
    for (int i = 0; i < 2; i++) {
      int c = tid + i * 256;
      int r = c >> 3, c0 = (c & 7) * 8;
      int4 vv = *(const int4*)(Vbf + base + (size_t)(kk + r) * 1024 + c0);
      alignas(16) u16 tmp[8];
      *(int4*)tmp = vv;
      #pragma unroll
      for (int d = 0; d < 8; d++) Vt[(c0 + d) * 72 + r] = tmp[d];
    }
    __syncthreads();

    f32x4 sacc[4] = {};
    #pragma unroll
    for (int ks = 0; ks < 2; ks++) {
      #pragma unroll
      for (int j = 0; j < 4; j++) {
        bf16x8 bk = *(const bf16x8*)&Ks[(j * 16 + l15) * 64 + ks * 32 + g * 8];
        sacc[j] = __builtin_amdgcn_mfma_f32_16x16x32_bf16(aq[ks], bk, sacc[j], 0, 0, 0);
      }
    }

    float sv[4][4];
    const bool diag = (kt == qt);
    #pragma unroll
    for (int j = 0; j < 4; j++) {
      int col = kk + j * 16 + l15;
      #pragma unroll
      for (int r = 0; r < 4; r++) {
        float s = sacc[j][r] * scale;
        if (diag) {
          int rowq = qbase + w * 16 + g * 4 + r;
          if (col > rowq) s = -1e30f;
        }
        sv[j][r] = s;
      }
    }
    #pragma unroll
    for (int r = 0; r < 4; r++) {
      float t0 = fmaxf(fmaxf(sv[0][r], sv[1][r]), fmaxf(sv[2][r], sv[3][r]));
      t0 = fmaxf(t0, __shfl_xor(t0, 1, 64));
      t0 = fmaxf(t0, __shfl_xor(t0, 2, 64));
      t0 = fmaxf(t0, __shfl_xor(t0, 4, 64));
      t0 = fmaxf(t0, __shfl_xor(t0, 8, 64));
      float mnew = fmaxf(m_i[r], t0);
      float alpha = __expf(m_i[r] - mnew);
      m_i[r] = mnew;
      l_i[r] *= alpha;
      acco[0][r] *= alpha; acco[1][r] *= alpha; acco[2][r] *= alpha; acco[3][r] *= alpha;
    }
    #pragma unroll
    for (int j = 0; j < 4; j++)
      #pragma unroll
      for (int r = 0; r < 4; r++)
        sv[j][r] = __expf(sv[j][r] - m_i[r]);
    #pragma unroll
    for (int r = 0; r < 4; r++) {
      float rs = sv[0][r] + sv[1][r] + sv[2][r] + sv[3][r];
      rs += __shfl_xor(rs, 1, 64);
      rs += __shfl_xor(rs, 2, 64);
      rs += __shfl_xor(rs, 4, 64);
      rs += __shfl_xor(rs, 8, 64);
      l_i[r] += rs;
    }
    #pragma unroll
    for (int j = 0; j < 4; j++)
      #pragma unroll
      for (int r = 0; r < 4; r++)
        Ps[w][(g * 4 + r) * 72 + j * 16 + l15] = f2bf(sv[j][r]);
    __syncthreads();
    #pragma unroll
    for (int ks = 0; ks < 2; ks++) {
      bf16x8 ap = *(const bf16x8*)&Ps[w][l15 * 72 + ks * 32 + g * 8];
      #pragma unroll
      for (int j = 0; j < 4; j++) {
        bf16x8 bv = *(const bf16x8*)&Vt[(j * 16 + l15) * 72 + ks * 32 + g * 8];
        acco[j] = __builtin_amdgcn_mfma_f32_16x16x32_bf16(ap, bv, acco[j], 0, 0, 0);
      }
    }
  }

  const float gh = gate[h];
  #pragma unroll
  for (int j = 0; j < 4; j++) {
    #pragma unroll
    for (int r = 0; r < 4; r++) {
      int rowq = qbase + w * 16 + g * 4 + r;
      size_t idx = base + (size_t)rowq * 1024 + j * 16 + l15;
      float val = acco[j][r] * (gh / l_i[r]) + bf2f(Vbf[idx]);
      O[idx] = f2bf(val);
    }
  }
}

// ---------------- host launch ----------------
extern "C" void kernel_launch(void* const* d_in, const int* in_sizes, int n_in,
                              void* d_out, int out_size, void* d_ws, size_t ws_size,
                              hipStream_t stream)
{
  const int*   ids  = (const int*)d_in[0];
  const float* emb  = (const float*)d_in[1];
  const float* pos  = (const float*)d_in[2];
  const float* Wq   = (const float*)d_in[3];
  const float* Wk   = (const float*)d_in[4];
  const float* Wv   = (const float*)d_in[5];
  const float* Wo   = (const float*)d_in[6];
  const float* ln1  = (const float*)d_in[7];
  const float* ln2  = (const float*)d_in[8];
  const float* qn   = (const float*)d_in[9];
  const float* kn   = (const float*)d_in[10];
  const float* gate = (const float*)d_in[11];
  const float* W1   = (const float*)d_in[12];
  const float* W2   = (const float*)d_in[13];
  const float* lnf  = (const float*)d_in[14];
  const float* Wlm  = (const float*)d_in[15];
  float* out = (float*)d_out;

  // workspace carve: base 68 MiB (as before) + 24 MiB layer-weight bf16 + 98.25 MiB Wlm^T
  char* wsb = (char*)d_ws;
  float* x    = (float*)(wsb);
  u16*   hbf  = (u16*)(wsb + (8u  << 20));
  float* qraw = (float*)(wsb + (12u << 20));
  float* kraw = (float*)(wsb + (20u << 20));
  float* vraw = (float*)(wsb + (28u << 20));
  u16*   qbf  = (u16*)(wsb + (36u << 20));
  u16*   kbf  = (u16*)(wsb + (40u << 20));
  u16*   vbf  = (u16*)(wsb + (44u << 20));
  u16*   o2   = (u16*)(wsb + (48u << 20));
  u16*   a1   = (u16*)(wsb + (52u << 20));

  const size_t MB = 1ull << 20;
  u16* wT   = (u16*)(wsb + 68 * MB);                  // 24 MiB: Wq,Wk,Wv,Wo^T (2MiB each) + W1^T (8) + W2^T (8)
  u16* wlmT = (u16*)(wsb + 92 * MB);                  // 50304 x 1024 bf16 = 98.25 MiB
  const bool useB  = ws_size >= 92 * MB;              // per-layer preconversion fits
  const bool useLM = ws_size >= 92 * MB + 103022592ull;

  u16* wq  = wT;
  u16* wk  = wT + 1 * 1048576;
  u16* wv  = wT + 2 * 1048576;
  u16* wo  = wT + 3 * 1048576;
  u16* w1t = wT + 4 * 1048576;                        // [4096][1024]
  u16* w2t = wT + 8 * 1048576;                        // [1024][4096]

  const size_t DD = 1024ull * 1024ull;
  const size_t DF = 1024ull * 4096ull;

  embed_k<<<2048, 256, 0, stream>>>(ids, emb, pos, x);

  for (int l = 0; l < 12; l++) {
    if (useB) {
      convw_k<<<dim3(16, 16, 4), 256, 0, stream>>>(Wq + l * DD, Wk + l * DD, Wv + l * DD,
                                                   Wo + l * DD, wT, 1024, 1024, 1048576);
      convw_k<<<dim3(16, 64, 1), 256, 0, stream>>>(W1 + l * DF, nullptr, nullptr, nullptr,
                                                   w1t, 1024, 4096, 0);
      convw_k<<<dim3(64, 16, 1), 256, 0, stream>>>(W2 + l * DF, nullptr, nullptr, nullptr,
                                                   w2t, 4096, 1024, 0);
    }
    rmsnorm_k<<<2048, 256, 0, stream>>>(x, ln1 + (size_t)l * 1024, hbf);
    if (useB) {
      gemm128b<<<dim3(128, 1, 3), 256, 0, stream>>>(hbf, wq, wk, wv, 1024, 1024,
                                                    qraw, nullptr, nullptr, EPI_F32,
                                                    (size_t)2048 * 1024);
    } else {
      gemm128<<<dim3(128, 1, 3), 256, 0, stream>>>(hbf, Wq + l * DD, Wk + l * DD, Wv + l * DD,
                                                   1024, 1024, qraw, nullptr, nullptr,
                                                   EPI_F32, (size_t)2048 * 1024);
    }
    qkvnorm_k<<<2048, 256, 0, stream>>>(qraw, kraw, vraw, qn + (size_t)l * 64, kn + (size_t)l * 64,
                                        qbf, kbf, vbf);
    attn_k<<<512, 256, 0, stream>>>(qbf, kbf, vbf, gate + (size_t)l * 16, o2);
    if (useB) {
      gemm128b<<<dim3(128, 1, 1), 256, 0, stream>>>(o2, wo, nullptr, nullptr, 1024, 1024,
                                                    x, nullptr, x, EPI_ADDRES, 0);
    } else {
      gemm128<<<dim3(128, 1, 1), 256, 0, stream>>>(o2, Wo + l * DD, nullptr, nullptr,
                                                   1024, 1024, x, nullptr, x, EPI_ADDRES, 0);
    }
    rmsnorm_k<<<2048, 256, 0, stream>>>(x, ln2 + (size_t)l * 1024, hbf);
    if (useB) {
      gemm128b<<<dim3(512, 1, 1), 256, 0, stream>>>(hbf, w1t, nullptr, nullptr, 4096, 1024,
                                                    x, a1, nullptr, EPI_GELU, 0);
      gemm128b<<<dim3(128, 1, 1), 256, 0, stream>>>(a1, w2t, nullptr, nullptr, 1024, 4096,
                                                    x, nullptr, x, EPI_ADDRES, 0);
    } else {
      gemm128<<<dim3(512, 1, 1), 256, 0, stream>>>(hbf, W1 + l * DF, nullptr, nullptr,
                                                   4096, 1024, x, a1, nullptr, EPI_GELU, 0);
      gemm128<<<dim3(128, 1, 1), 256, 0, stream>>>(a1, W2 + l * DF, nullptr, nullptr,
                                                   1024, 4096, x, nullptr, x, EPI_ADDRES, 0);
    }
  }

  rmsnorm_k<<<2048, 256, 0, stream>>>(x, lnf, hbf);
  if (useLM) {
    convw_k<<<dim3(16, 786, 1), 256, 0, stream>>>(Wlm, nullptr, nullptr, nullptr,
                                                  wlmT, 1024, 50257, 0);
    gemm128b<<<dim3(6288, 1, 1), 256, 0, stream>>>(hbf, wlmT, nullptr, nullptr, 50257, 1024,
                                                   out, nullptr, nullptr, EPI_F32, 0);
  } else {
    gemm128<<<dim3(6288, 1, 1), 256, 0, stream>>>(hbf, Wlm, nullptr, nullptr,
                                                  50257, 1024, out, nullptr, nullptr, EPI_F32, 0);
  }
}